// Round 2
// baseline (96.428 us; speedup 1.0000x reference)
//
#include <hip/hip_runtime.h>
#include <cmath>

#define B_  16
#define S_  512
#define DI  64
#define DS  64
#define RR  4
#define CH  8      // chunks
#define CL  64     // chunk length

// ws layout (floats):
#define WS_U    524288        // u     [B*S][DI]
#define WS_BM   1048576       // bm    [B*S][DS]
#define WS_CML  1572864       // cml   [B][DS]
#define WS_HIN  1573888       // h_in  [B][CH][DI][DS]
// total 2,098,176 floats ~= 8.4 MB

// chunk summaries (4 arrays of 524288 floats = 8 MB) live in the d_out h-region
// (out+1024 ...): written by k2a, read by k2b, overwritten by k2c. Kernel
// boundaries on the stream order these accesses; no race.
#define SUMN 524288

__global__ __launch_bounds__(64)
void ssm_k1(const float* __restrict__ x, const float* __restrict__ Wx,
            const float* __restrict__ bx, const float* __restrict__ Wdt,
            const float* __restrict__ bdt, const float* __restrict__ A_log,
            float* __restrict__ ws)
{
    __shared__ float xs[DI];
    __shared__ float aa_s[DS];
    __shared__ float dtr_s[RR];
    const int bt   = blockIdx.x;      // b*S + t
    const int lane = threadIdx.x;     // 0..63

    const float xv = x[bt * DI + lane];
    xs[lane]   = xv;
    aa_s[lane] = -expf(A_log[lane]);  // row 0 of A_log (all rows identical)
    __syncthreads();

    // Bm column (proj col = lane)
    float accB = bx[lane];
    {
        const float* wr = Wx + lane * DI;
        #pragma unroll
        for (int i = 0; i < DI; i += 4) {
            float4 w = *reinterpret_cast<const float4*>(wr + i);
            accB += w.x * xs[i] + w.y * xs[i + 1] + w.z * xs[i + 2] + w.w * xs[i + 3];
        }
    }
    // dtr (proj cols DS..DS+3), lanes 0..3
    if (lane < RR) {
        float acc = bx[DS + lane];
        const float* wr = Wx + (DS + lane) * DI;
        #pragma unroll
        for (int i = 0; i < DI; i += 4) {
            float4 w = *reinterpret_cast<const float4*>(wr + i);
            acc += w.x * xs[i] + w.y * xs[i + 1] + w.z * xs[i + 2] + w.w * xs[i + 3];
        }
        dtr_s[lane] = acc;
    }
    __syncthreads();

    // dt for d = lane
    float dtv = bdt[lane];
    #pragma unroll
    for (int r = 0; r < RR; ++r) dtv += dtr_s[r] * Wdt[lane * RR + r];

    const float a_l = aa_s[lane];

    // s = sum_d a[d]*dt[d],  asq = |a|^2  (64-lane butterfly)
    float sv = a_l * dtv;
    float qv = a_l * a_l;
    #pragma unroll
    for (int off = 32; off > 0; off >>= 1) {
        sv += __shfl_xor(sv, off);
        qv += __shfl_xor(qv, off);
    }

    const float E   = expm1f(sv);
    const float phi = (fabsf(sv) < 1e-3f)
                        ? fmaf(sv, fmaf(sv, 1.0f / 6.0f, 0.5f), 1.0f)
                        : (E / sv);

    ws[bt * DI + lane]          = phi * dtv;          // phidt
    ws[WS_U + bt * DI + lane]   = xv * (E / qv) * a_l; // u
    ws[WS_BM + bt * DI + lane]  = accB;                // bm

    if ((bt & (S_ - 1)) == (S_ - 1)) {
        float accC = bx[DS + RR + lane];
        const float* wr = Wx + (DS + RR + lane) * DI;
        #pragma unroll
        for (int i = 0; i < DI; i += 4) {
            float4 w = *reinterpret_cast<const float4*>(wr + i);
            accC += w.x * xs[i] + w.y * xs[i + 1] + w.z * xs[i + 2] + w.w * xs[i + 3];
        }
        ws[WS_CML + (bt >> 9) * DS + lane] = accC;   // bt>>9 == b
    }
}

// k2a: per (b,d,n,chunk) affine chunk summary (no clip):
//   p = prod av, q = affine offset, Pm = max_t |p_t|, Qm = max_t qabs_t
__global__ __launch_bounds__(256)
void ssm_k2a(const float* __restrict__ ws, const float* __restrict__ A_log,
             float* __restrict__ out)
{
    const int tid  = threadIdx.x;
    const int n    = tid & 63;
    const int d    = ((blockIdx.x >> 3) & 15) * 4 + (tid >> 6);
    const int c    = blockIdx.x & 7;
    const int b    = blockIdx.x >> 7;

    const float a_n   = -expf(A_log[n]);
    const float delta = (d == n) ? 1.0f : 0.0f;

    const float* phidt = ws + (size_t)(b * S_) * DI + d;
    const float* uws   = ws + WS_U + (size_t)(b * S_) * DI + d;
    const float* bmws  = ws + WS_BM + (size_t)(b * S_) * DI + n;

    const int t0 = c * CL;
    float p = 1.0f, q = 0.0f, qa = 0.0f, Pm = 0.0f, Qm = 0.0f;
    #pragma unroll 8
    for (int j = 0; j < CL; ++j) {
        const int t = t0 + j;
        const float pv = phidt[(size_t)t * DI];
        const float uv = uws[(size_t)t * DI];
        const float bv = bmws[(size_t)t * DI];
        const float av = fmaf(pv, a_n, delta);
        const float w  = uv * bv;
        p  = p * av;
        q  = fmaf(av, q, w);
        qa = fmaf(fabsf(av), qa, fabsf(w));
        Pm = fmaxf(Pm, fabsf(p));
        Qm = fmaxf(Qm, qa);
    }
    const size_t si = (((size_t)b * CH + c) * DI + d) * DS + n;
    float* sum = out + 1024;
    sum[si]            = p;
    sum[SUMN + si]     = q;
    sum[2 * SUMN + si] = Pm;
    sum[3 * SUMN + si] = Qm;
}

// k2b: sequential scan over chunks; linear fast-path when provably clip-free,
// exact 64-step replay otherwise. Writes chunk-entry h to ws.
__global__ __launch_bounds__(256)
void ssm_k2b(float* __restrict__ ws, const float* __restrict__ out,
             const float* __restrict__ A_log)
{
    const int tid = threadIdx.x;
    const int n   = tid & 63;
    const int d   = (blockIdx.x & 15) * 4 + (tid >> 6);
    const int b   = blockIdx.x >> 4;

    const float a_n   = -expf(A_log[n]);
    const float delta = (d == n) ? 1.0f : 0.0f;

    const float* sum   = out + 1024;
    const float* phidt = ws + (size_t)(b * S_) * DI + d;
    const float* uws   = ws + WS_U + (size_t)(b * S_) * DI + d;
    const float* bmws  = ws + WS_BM + (size_t)(b * S_) * DI + n;
    float* hin = ws + WS_HIN;

    float h = 0.0f;
    for (int c = 0; c < CH; ++c) {
        const size_t si = (((size_t)b * CH + c) * DI + d) * DS + n;
        hin[si] = h;
        const float Pm = sum[2 * SUMN + si];
        const float Qm = sum[3 * SUMN + si];
        const float bound = fmaf(Pm, fabsf(h), Qm);
        if (bound <= 1.0e6f) {   // NaN/inf -> false -> replay
            h = fmaf(sum[si], h, sum[SUMN + si]);
            h = fminf(fmaxf(h, -1.0e6f), 1.0e6f);
        } else {
            const int t0 = c * CL;
            #pragma unroll 8
            for (int j = 0; j < CL; ++j) {
                const int t = t0 + j;
                const float av = fmaf(phidt[(size_t)t * DI], a_n, delta);
                const float w  = uws[(size_t)t * DI] * bmws[(size_t)t * DI];
                h = fmaf(av, h, w);
                h = fminf(fmaxf(h, -1.0e6f), 1.0e6f);
            }
        }
    }
}

// k2c: full-occupancy replay per (b,d,n,chunk) from h_in; streams all h out.
__global__ __launch_bounds__(256)
void ssm_k2c(const float* __restrict__ ws, const float* __restrict__ x,
             const float* __restrict__ A_log, const float* __restrict__ Dp,
             float* __restrict__ out)
{
    const int tid = threadIdx.x;
    const int n   = tid & 63;
    const int d   = ((blockIdx.x >> 3) & 15) * 4 + (tid >> 6);
    const int c   = blockIdx.x & 7;
    const int b   = blockIdx.x >> 7;

    const float a_n   = -expf(A_log[n]);
    const float delta = (d == n) ? 1.0f : 0.0f;

    const float* phidt = ws + (size_t)(b * S_) * DI + d;
    const float* uws   = ws + WS_U + (size_t)(b * S_) * DI + d;
    const float* bmws  = ws + WS_BM + (size_t)(b * S_) * DI + n;

    const size_t si = (((size_t)b * CH + c) * DI + d) * DS + n;
    float h = ws[WS_HIN + si];

    float* po = out + 1024 + (size_t)(b * S_) * (DI * DS) + d * DS + n;
    const int t0 = c * CL;
    #pragma unroll 8
    for (int j = 0; j < CL; ++j) {
        const int t = t0 + j;
        const float pv = phidt[(size_t)t * DI];
        const float uv = uws[(size_t)t * DI];
        const float bv = bmws[(size_t)t * DI];
        const float av = fmaf(pv, a_n, delta);
        h = fmaf(av, h, uv * bv);
        h = fminf(fmaxf(h, -1.0e6f), 1.0e6f);
        po[(size_t)t * (DI * DS)] = h;
    }

    if (c == CH - 1) {
        // y[-1]: reduce h*Cm over n (one wave == one (b,d) row)
        float v = h * ws[WS_CML + b * DS + n];
        #pragma unroll
        for (int off = 32; off > 0; off >>= 1) v += __shfl_xor(v, off);
        if (n == 0) {
            const float xi = x[((b * S_) + S_ - 1) * DI + d];
            out[b * DI + d] = v + Dp[d] * xi;
        }
    }
}

extern "C" void kernel_launch(void* const* d_in, const int* in_sizes, int n_in,
                              void* d_out, int out_size, void* d_ws, size_t ws_size,
                              hipStream_t stream)
{
    const float* x     = (const float*)d_in[0];
    const float* Wx    = (const float*)d_in[1];
    const float* bx    = (const float*)d_in[2];
    const float* Wdt   = (const float*)d_in[3];
    const float* bdt   = (const float*)d_in[4];
    const float* A_log = (const float*)d_in[5];
    const float* Dp    = (const float*)d_in[6];
    float* out = (float*)d_out;
    float* ws  = (float*)d_ws;

    ssm_k1 <<<B_ * S_, 64, 0, stream>>>(x, Wx, bx, Wdt, bdt, A_log, ws);
    ssm_k2a<<<B_ * 16 * CH, 256, 0, stream>>>(ws, A_log, out);
    ssm_k2b<<<B_ * 16, 256, 0, stream>>>(ws, out, A_log);
    ssm_k2c<<<B_ * 16 * CH, 256, 0, stream>>>(ws, x, A_log, Dp, out);
}

// Round 3
// 70.704 us; speedup vs baseline: 1.3638x; 1.3638x over previous
//
#include <hip/hip_runtime.h>
#include <cmath>

#define B_  16
#define S_  512
#define DI  64
#define DS  64
#define RR  4
#define CH  8      // chunks
#define CL  64     // chunk length
#define CLIPM 1.0e6f

// ws layout (floats):
#define WS_U    524288        // u     [B*S][DI]
#define WS_BM   1048576       // bm    [B*S][DS]
#define WS_CML  1572864       // cml   [B][DS]
#define WS_HIN  1573888       // h_in  [B][CH][DI][DS]
// total 2,098,176 floats ~= 8.4 MB

// chunk summaries (4 arrays of 524288 floats = 8 MB) live in the d_out h-region
// (out+1024 ...): written by k2a, read by k2b, overwritten by k2c. Kernel
// boundaries on the stream order these accesses; no race.
#define SUMN 524288

__device__ __forceinline__ float clampM(float v) {
    return fminf(fmaxf(v, -CLIPM), CLIPM);
}

__global__ __launch_bounds__(64)
void ssm_k1(const float* __restrict__ x, const float* __restrict__ Wx,
            const float* __restrict__ bx, const float* __restrict__ Wdt,
            const float* __restrict__ bdt, const float* __restrict__ A_log,
            float* __restrict__ ws)
{
    __shared__ float xs[DI];
    __shared__ float aa_s[DS];
    __shared__ float dtr_s[RR];
    const int bt   = blockIdx.x;      // b*S + t
    const int lane = threadIdx.x;     // 0..63

    const float xv = x[bt * DI + lane];
    xs[lane]   = xv;
    aa_s[lane] = -expf(A_log[lane]);  // row 0 of A_log (all rows identical)
    __syncthreads();

    // Bm column (proj col = lane)
    float accB = bx[lane];
    {
        const float* wr = Wx + lane * DI;
        #pragma unroll
        for (int i = 0; i < DI; i += 4) {
            float4 w = *reinterpret_cast<const float4*>(wr + i);
            accB += w.x * xs[i] + w.y * xs[i + 1] + w.z * xs[i + 2] + w.w * xs[i + 3];
        }
    }
    // dtr (proj cols DS..DS+3), lanes 0..3
    if (lane < RR) {
        float acc = bx[DS + lane];
        const float* wr = Wx + (DS + lane) * DI;
        #pragma unroll
        for (int i = 0; i < DI; i += 4) {
            float4 w = *reinterpret_cast<const float4*>(wr + i);
            acc += w.x * xs[i] + w.y * xs[i + 1] + w.z * xs[i + 2] + w.w * xs[i + 3];
        }
        dtr_s[lane] = acc;
    }
    __syncthreads();

    // dt for d = lane
    float dtv = bdt[lane];
    #pragma unroll
    for (int r = 0; r < RR; ++r) dtv += dtr_s[r] * Wdt[lane * RR + r];

    const float a_l = aa_s[lane];

    // s = sum_d a[d]*dt[d],  asq = |a|^2  (64-lane butterfly)
    float sv = a_l * dtv;
    float qv = a_l * a_l;
    #pragma unroll
    for (int off = 32; off > 0; off >>= 1) {
        sv += __shfl_xor(sv, off);
        qv += __shfl_xor(qv, off);
    }

    const float E   = expm1f(sv);
    const float phi = (fabsf(sv) < 1e-3f)
                        ? fmaf(sv, fmaf(sv, 1.0f / 6.0f, 0.5f), 1.0f)
                        : (E / sv);

    ws[bt * DI + lane]          = phi * dtv;           // phidt
    ws[WS_U + bt * DI + lane]   = xv * (E / qv) * a_l; // u
    ws[WS_BM + bt * DI + lane]  = accB;                // bm

    if ((bt & (S_ - 1)) == (S_ - 1)) {
        float accC = bx[DS + RR + lane];
        const float* wr = Wx + (DS + RR + lane) * DI;
        #pragma unroll
        for (int i = 0; i < DI; i += 4) {
            float4 w = *reinterpret_cast<const float4*>(wr + i);
            accC += w.x * xs[i] + w.y * xs[i + 1] + w.z * xs[i + 2] + w.w * xs[i + 3];
        }
        ws[WS_CML + (bt >> 9) * DS + lane] = accC;   // bt>>9 == b
    }
}

// k2a: EXACT chunk summary. The composition of t -> clip(av*h + w, -M, M)
// over a chunk is exactly h -> clamp(alpha*h + beta, lo, hi) (monotone PL map
// with one linear middle piece; min/max swap handles negative slopes).
__global__ __launch_bounds__(256)
void ssm_k2a(const float* __restrict__ ws, const float* __restrict__ A_log,
             float* __restrict__ out)
{
    const int tid  = threadIdx.x;
    const int n    = tid & 63;
    const int d    = ((blockIdx.x >> 3) & 15) * 4 + (tid >> 6);
    const int c    = blockIdx.x & 7;
    const int b    = blockIdx.x >> 7;

    const float a_n   = -expf(A_log[n]);
    const float delta = (d == n) ? 1.0f : 0.0f;

    const float* phidt = ws + (size_t)(b * S_) * DI + d;
    const float* uws   = ws + WS_U + (size_t)(b * S_) * DI + d;
    const float* bmws  = ws + WS_BM + (size_t)(b * S_) * DI + n;

    const int t0 = c * CL;
    // identity on the domain [-M, M] (h_in always lies there)
    float alpha = 1.0f, beta = 0.0f, lo = -CLIPM, hi = CLIPM;
    #pragma unroll 8
    for (int j = 0; j < CL; ++j) {
        const int t = t0 + j;
        const float pv = phidt[(size_t)t * DI];
        const float uv = uws[(size_t)t * DI];
        const float bv = bmws[(size_t)t * DI];
        const float av = fmaf(pv, a_n, delta);
        const float w  = uv * bv;
        alpha = av * alpha;
        beta  = fmaf(av, beta, w);
        const float t1 = fmaf(av, lo, w);
        const float t2 = fmaf(av, hi, w);
        lo = clampM(fminf(t1, t2));
        hi = clampM(fmaxf(t1, t2));
    }
    const size_t si = (((size_t)b * CH + c) * DI + d) * DS + n;
    float* sum = out + 1024;
    sum[si]            = alpha;
    sum[SUMN + si]     = beta;
    sum[2 * SUMN + si] = lo;
    sum[3 * SUMN + si] = hi;
}

// k2b: sequential scan over the 8 chunk summaries — exact, no replay.
__global__ __launch_bounds__(256)
void ssm_k2b(float* __restrict__ ws, const float* __restrict__ out)
{
    const int tid = threadIdx.x;
    const int n   = tid & 63;
    const int d   = (blockIdx.x & 15) * 4 + (tid >> 6);
    const int b   = blockIdx.x >> 4;

    const float* sum = out + 1024;
    float* hin = ws + WS_HIN;

    float h = 0.0f;
    #pragma unroll
    for (int c = 0; c < CH; ++c) {
        const size_t si = (((size_t)b * CH + c) * DI + d) * DS + n;
        hin[si] = h;
        const float alpha = sum[si];
        const float beta  = sum[SUMN + si];
        const float lo    = sum[2 * SUMN + si];
        const float hi    = sum[3 * SUMN + si];
        h = fminf(fmaxf(fmaf(alpha, h, beta), lo), hi);
    }
}

// k2c: full-occupancy replay per (b,d,n,chunk) from h_in; streams all h out.
__global__ __launch_bounds__(256)
void ssm_k2c(const float* __restrict__ ws, const float* __restrict__ x,
             const float* __restrict__ A_log, const float* __restrict__ Dp,
             float* __restrict__ out)
{
    const int tid = threadIdx.x;
    const int n   = tid & 63;
    const int d   = ((blockIdx.x >> 3) & 15) * 4 + (tid >> 6);
    const int c   = blockIdx.x & 7;
    const int b   = blockIdx.x >> 7;

    const float a_n   = -expf(A_log[n]);
    const float delta = (d == n) ? 1.0f : 0.0f;

    const float* phidt = ws + (size_t)(b * S_) * DI + d;
    const float* uws   = ws + WS_U + (size_t)(b * S_) * DI + d;
    const float* bmws  = ws + WS_BM + (size_t)(b * S_) * DI + n;

    const size_t si = (((size_t)b * CH + c) * DI + d) * DS + n;
    float h = ws[WS_HIN + si];

    float* po = out + 1024 + (size_t)(b * S_) * (DI * DS) + d * DS + n;
    const int t0 = c * CL;
    #pragma unroll 8
    for (int j = 0; j < CL; ++j) {
        const int t = t0 + j;
        const float pv = phidt[(size_t)t * DI];
        const float uv = uws[(size_t)t * DI];
        const float bv = bmws[(size_t)t * DI];
        const float av = fmaf(pv, a_n, delta);
        h = fmaf(av, h, uv * bv);
        h = clampM(h);
        po[(size_t)t * (DI * DS)] = h;
    }

    if (c == CH - 1) {
        // y[-1]: reduce h*Cm over n (one wave == one (b,d) row)
        float v = h * ws[WS_CML + b * DS + n];
        #pragma unroll
        for (int off = 32; off > 0; off >>= 1) v += __shfl_xor(v, off);
        if (n == 0) {
            const float xi = x[((b * S_) + S_ - 1) * DI + d];
            out[b * DI + d] = v + Dp[d] * xi;
        }
    }
}

extern "C" void kernel_launch(void* const* d_in, const int* in_sizes, int n_in,
                              void* d_out, int out_size, void* d_ws, size_t ws_size,
                              hipStream_t stream)
{
    const float* x     = (const float*)d_in[0];
    const float* Wx    = (const float*)d_in[1];
    const float* bx    = (const float*)d_in[2];
    const float* Wdt   = (const float*)d_in[3];
    const float* bdt   = (const float*)d_in[4];
    const float* A_log = (const float*)d_in[5];
    const float* Dp    = (const float*)d_in[6];
    float* out = (float*)d_out;
    float* ws  = (float*)d_ws;

    ssm_k1 <<<B_ * S_, 64, 0, stream>>>(x, Wx, bx, Wdt, bdt, A_log, ws);
    ssm_k2a<<<B_ * 16 * CH, 256, 0, stream>>>(ws, A_log, out);
    ssm_k2b<<<B_ * 16, 256, 0, stream>>>(ws, out);
    ssm_k2c<<<B_ * 16 * CH, 256, 0, stream>>>(ws, x, A_log, Dp, out);
}